// Round 1
// baseline (689.302 us; speedup 1.0000x reference)
//
#include <hip/hip_runtime.h>
#include <cstdint>
#include <cstddef>

using u16 = unsigned short;
typedef float f32x4 __attribute__((ext_vector_type(4)));
typedef __bf16 bf16x8 __attribute__((ext_vector_type(8)));

constexpr int BB = 1024;   // batch
constexpr int TT = 100;    // timesteps
constexpr int MMIN = 120;  // input features
constexpr int HH = 512;    // hidden
constexpr int DD = 12;     // output classes

__device__ __forceinline__ u16 f2bf_rne(float x) {
  unsigned u = __float_as_uint(x);
  unsigned r = (u + 0x7FFFu + ((u >> 16) & 1u)) >> 16;
  return (u16)r;
}
__device__ __forceinline__ float bf2f(u16 u) {
  return __uint_as_float(((unsigned)u) << 16);
}

// ---------- weight transpose + hi/lo split:  T[n][k] = W[k][n] ----------
__global__ __launch_bounds__(256) void wsplit_kernel(
    const float* __restrict__ W, u16* __restrict__ Thi, u16* __restrict__ Tlo,
    int K, int N, int kp_shift) {
  int gid = blockIdx.x * 256 + threadIdx.x;
  int KP = 1 << kp_shift;
  int k = gid & (KP - 1);
  int n = gid >> kp_shift;
  float v = 0.0f;
  if (k < K && n < N) v = W[(size_t)k * N + n];
  u16 hi = f2bf_rne(v);
  Thi[gid] = hi;
  Tlo[gid] = f2bf_rne(v - bf2f(hi));
}

// ---------- x: (B,1,T,M) -> rows r=t*B+b of [r][128] (pad 120->128), hi/lo split ----------
__global__ __launch_bounds__(256) void xsplit_kernel(
    const float* __restrict__ x, u16* __restrict__ xhi, u16* __restrict__ xlo, int t0) {
  int gid = blockIdx.x * 256 + threadIdx.x;
  int m = gid & 127;
  int r = gid >> 7;               // local row within chunk
  int b = r & (BB - 1);
  int t = t0 + (r >> 10);
  float v = 0.0f;
  if (m < MMIN) v = x[(size_t)b * (TT * MMIN) + (size_t)t * MMIN + m];
  u16 hi = f2bf_rne(v);
  xhi[gid] = hi;
  xlo[gid] = f2bf_rne(v - bf2f(hi));
}

// ---------- async global->LDS staging with XOR chunk swizzle ----------
typedef const __attribute__((address_space(1))) unsigned int gas_uint;
typedef __attribute__((address_space(3))) unsigned int las_uint;

__device__ __forceinline__ void gl_lds16(const void* g, void* l) {
  __builtin_amdgcn_global_load_lds((gas_uint*)g, (las_uint*)l, 16, 0, 0);
}

// stage a 128x64 bf16 tile from row-major src (leading dim ld) into LDS.
// LDS[r][chunk c] holds global chunk (c ^ (r&7))  (16B chunks, 8 per row).
__device__ __forceinline__ void stage_tile(const u16* __restrict__ src, int ld,
                                           size_t row0, int k0, u16* lds, int tid) {
#pragma unroll
  for (int p = 0; p < 4; ++p) {
    int li = p * 256 + tid;
    int r = li >> 3;
    int c = li & 7;
    int cs = c ^ (r & 7);
    const u16* g = src + (row0 + (size_t)r) * (size_t)ld + k0 + cs * 8;
    u16* l = lds + (size_t)(li & ~63) * 8;   // wave-uniform base; HW adds lane*16
    gl_lds16(g, l);
  }
}

// ---------- split-precision MFMA GEMM:  C = sum(terms) A?@B?  ----------
// A: MxK row-major bf16.  Bhi/Blo: NxK row-major bf16 (i.e. B^T).  C: MxN f32.
// TERMS==2: Ahi@Bhi + Ahi@Blo (A exact, e.g. binary spikes)
// TERMS==3: + Alo@Bhi (for non-exact A, e.g. the f32 input x)
template <int TERMS>
__global__ __launch_bounds__(256) void gemm_tile(
    const u16* __restrict__ Ahi, const u16* __restrict__ Alo,
    const u16* __restrict__ Bhi, const u16* __restrict__ Blo,
    float* __restrict__ C, int M, int N, int K, int Nt) {
  __shared__ __align__(16) u16 sAh[128 * 64];
  __shared__ __align__(16) u16 sBh[128 * 64];
  __shared__ __align__(16) u16 sBl[128 * 64];
  __shared__ __align__(16) u16 sAl[TERMS == 3 ? 128 * 64 : 8];

  const int tid = threadIdx.x;
  const int bn = blockIdx.x % Nt;
  const int bm = blockIdx.x / Nt;
  const int lane = tid & 63;
  const int wv = tid >> 6;
  const int wm = wv >> 1, wn = wv & 1;
  const int lr = lane & 15, lg = lane >> 4;

  f32x4 acc[4][4];
#pragma unroll
  for (int i = 0; i < 4; ++i)
#pragma unroll
    for (int j = 0; j < 4; ++j) acc[i][j] = (f32x4)0.0f;

  const size_t arow0 = (size_t)bm * 128;
  const size_t brow0 = (size_t)bn * 128;

  for (int kt = 0; kt < K; kt += 64) {
    __syncthreads();
    stage_tile(Ahi, K, arow0, kt, sAh, tid);
    if constexpr (TERMS == 3) stage_tile(Alo, K, arow0, kt, sAl, tid);
    stage_tile(Bhi, K, brow0, kt, sBh, tid);
    stage_tile(Blo, K, brow0, kt, sBl, tid);
    __syncthreads();   // compiler inserts s_waitcnt vmcnt(0) before s_barrier

#pragma unroll
    for (int kk = 0; kk < 2; ++kk) {   // two 32-wide MFMA K-slices per 64-tile
      bf16x8 a0[4], a1[4], bh[4], bl[4];
#pragma unroll
      for (int mf = 0; mf < 4; ++mf) {
        int r = wm * 64 + mf * 16 + lr;
        int cg = kk * 4 + lg;
        int o = r * 64 + ((cg ^ (r & 7)) << 3);
        a0[mf] = *(const bf16x8*)&sAh[o];
        if constexpr (TERMS == 3) a1[mf] = *(const bf16x8*)&sAl[o];
      }
#pragma unroll
      for (int nf = 0; nf < 4; ++nf) {
        int r = wn * 64 + nf * 16 + lr;
        int cg = kk * 4 + lg;
        int o = r * 64 + ((cg ^ (r & 7)) << 3);
        bh[nf] = *(const bf16x8*)&sBh[o];
        bl[nf] = *(const bf16x8*)&sBl[o];
      }
#pragma unroll
      for (int mf = 0; mf < 4; ++mf)
#pragma unroll
        for (int nf = 0; nf < 4; ++nf) {
          acc[mf][nf] = __builtin_amdgcn_mfma_f32_16x16x32_bf16(a0[mf], bh[nf], acc[mf][nf], 0, 0, 0);
          acc[mf][nf] = __builtin_amdgcn_mfma_f32_16x16x32_bf16(a0[mf], bl[nf], acc[mf][nf], 0, 0, 0);
          if constexpr (TERMS == 3)
            acc[mf][nf] = __builtin_amdgcn_mfma_f32_16x16x32_bf16(a1[mf], bh[nf], acc[mf][nf], 0, 0, 0);
        }
    }
  }

  // epilogue: C/D layout col=lane&15, row=(lane>>4)*4+j  (m89-verified)
#pragma unroll
  for (int mf = 0; mf < 4; ++mf) {
#pragma unroll
    for (int nf = 0; nf < 4; ++nf) {
      size_t row = arow0 + wm * 64 + mf * 16 + lg * 4;
      size_t col = brow0 + wn * 64 + nf * 16 + lr;
#pragma unroll
      for (int j = 0; j < 4; ++j) C[(row + j) * (size_t)N + col] = acc[mf][nf][j];
    }
  }
}

// ---------- LIF elementwise scan over the chunk's timesteps ----------
__global__ __launch_bounds__(256) void lif_kernel(
    const float4* __restrict__ I, const float* __restrict__ bias,
    float* __restrict__ vstate, ushort4* __restrict__ S, int TC, int firstc) {
  int gid = blockIdx.x * 256 + threadIdx.x;   // B*H/4 = 131072 threads
  int h4 = gid & 127;
  int b = gid >> 7;
  float4 bi = ((const float4*)bias)[h4];
  float4 v;
  if (firstc) { v.x = 0.f; v.y = 0.f; v.z = 0.f; v.w = 0.f; }
  else v = ((const float4*)vstate)[gid];
  for (int t = 0; t < TC; ++t) {
    size_t o = ((size_t)t * BB + b) * 128 + h4;   // float4 units
    float4 iv = I[o];
    ushort4 s;
    v.x += (iv.x + bi.x - v.x) * 0.5f;
    v.y += (iv.y + bi.y - v.y) * 0.5f;
    v.z += (iv.z + bi.z - v.z) * 0.5f;
    v.w += (iv.w + bi.w - v.w) * 0.5f;
    s.x = (v.x >= 1.0f) ? (u16)0x3F80 : (u16)0;
    s.y = (v.y >= 1.0f) ? (u16)0x3F80 : (u16)0;
    s.z = (v.z >= 1.0f) ? (u16)0x3F80 : (u16)0;
    s.w = (v.w >= 1.0f) ? (u16)0x3F80 : (u16)0;
    if (v.x >= 1.0f) v.x = 0.0f;
    if (v.y >= 1.0f) v.y = 0.0f;
    if (v.z >= 1.0f) v.z = 0.0f;
    if (v.w >= 1.0f) v.w = 0.0f;
    S[o] = s;
  }
  ((float4*)vstate)[gid] = v;
}

// ---------- readout EMA over chunk (carries mem & running sum) ----------
__global__ __launch_bounds__(256) void memscan_kernel(
    const float* __restrict__ R, const float* __restrict__ br,
    const float* __restrict__ tau, float* __restrict__ mstate,
    float* __restrict__ sstate, int TC, int firstc) {
  int b = blockIdx.x * 256 + threadIdx.x;   // 1024 threads
  float mem[DD], sum[DD], al[DD], bb[DD];
#pragma unroll
  for (int d = 0; d < DD; ++d) {
    al[d] = 1.0f / (1.0f + expf(-tau[d]));
    bb[d] = br[d];
  }
  if (firstc) {
#pragma unroll
    for (int d = 0; d < DD; ++d) { mem[d] = 0.0f; sum[d] = 0.0f; }
  } else {
#pragma unroll
    for (int d = 0; d < DD; ++d) { mem[d] = mstate[b * DD + d]; sum[d] = sstate[b * DD + d]; }
  }
  for (int t = 0; t < TC; ++t) {
    const float4* q = (const float4*)(R + ((size_t)t * BB + b) * 128);
    float4 q0 = q[0], q1 = q[1], q2 = q[2];
    float r[DD] = {q0.x, q0.y, q0.z, q0.w, q1.x, q1.y, q1.z, q1.w, q2.x, q2.y, q2.z, q2.w};
#pragma unroll
    for (int d = 0; d < DD; ++d) {
      float rv = r[d] + bb[d];
      mem[d] = mem[d] * al[d] + (1.0f - al[d]) * rv;
      sum[d] += mem[d];
    }
  }
#pragma unroll
  for (int d = 0; d < DD; ++d) { mstate[b * DD + d] = mem[d]; sstate[b * DD + d] = sum[d]; }
}

// ---------- mean over T + log_softmax ----------
__global__ __launch_bounds__(256) void finalize_kernel(
    const float* __restrict__ ss, float* __restrict__ out) {
  int b = blockIdx.x * 256 + threadIdx.x;   // 1024 threads
  float l[DD];
#pragma unroll
  for (int d = 0; d < DD; ++d) l[d] = ss[b * DD + d] * (1.0f / (float)TT);
  float m = l[0];
#pragma unroll
  for (int d = 1; d < DD; ++d) m = fmaxf(m, l[d]);
  float s = 0.0f;
#pragma unroll
  for (int d = 0; d < DD; ++d) s += expf(l[d] - m);
  float lse = logf(s);
#pragma unroll
  for (int d = 0; d < DD; ++d) out[b * DD + d] = l[d] - m - lse;
}

extern "C" void kernel_launch(void* const* d_in, const int* in_sizes, int n_in,
                              void* d_out, int out_size, void* d_ws, size_t ws_size,
                              hipStream_t stream) {
  (void)in_sizes; (void)n_in; (void)out_size;
  const float* x   = (const float*)d_in[0];
  const float* W1  = (const float*)d_in[1];
  const float* b1  = (const float*)d_in[2];
  const float* W2  = (const float*)d_in[3];
  const float* b2  = (const float*)d_in[4];
  const float* W3  = (const float*)d_in[5];
  const float* b3  = (const float*)d_in[6];
  const float* Wr  = (const float*)d_in[7];
  const float* br  = (const float*)d_in[8];
  const float* tau = (const float*)d_in[9];
  float* out = (float*)d_out;

  // pick largest time-chunk TC (divides 100) whose workspace fits
  const size_t fixed_bytes = 9011200;        // weight splits + v states + mem/sum states
  const size_t per_tc = 6291456;             // xhi/xlo + I + S1..3 + R per timestep
  int TC = 1;
  const int cands[9] = {100, 50, 25, 20, 10, 5, 4, 2, 1};
  for (int i = 0; i < 9; ++i) {
    if (fixed_bytes + (size_t)cands[i] * per_tc + 65536 <= ws_size) { TC = cands[i]; break; }
  }

  char* base = (char*)d_ws;
  size_t off = 0;
  auto alloc = [&](size_t bytes) -> char* {
    char* p = base + off;
    off += (bytes + 255) & ~(size_t)255;
    return p;
  };

  u16* W1Th = (u16*)alloc(512 * 128 * 2);
  u16* W1Tl = (u16*)alloc(512 * 128 * 2);
  u16* W2Th = (u16*)alloc(512 * 512 * 2);
  u16* W2Tl = (u16*)alloc(512 * 512 * 2);
  u16* W3Th = (u16*)alloc(512 * 512 * 2);
  u16* W3Tl = (u16*)alloc(512 * 512 * 2);
  u16* WrTh = (u16*)alloc(128 * 512 * 2);
  u16* WrTl = (u16*)alloc(128 * 512 * 2);
  float* v1 = (float*)alloc((size_t)BB * HH * 4);
  float* v2 = (float*)alloc((size_t)BB * HH * 4);
  float* v3 = (float*)alloc((size_t)BB * HH * 4);
  float* mstate = (float*)alloc((size_t)BB * DD * 4);
  float* sstate = (float*)alloc((size_t)BB * DD * 4);
  u16* xh = (u16*)alloc((size_t)TC * BB * 128 * 2);
  u16* xl = (u16*)alloc((size_t)TC * BB * 128 * 2);
  float* Ibuf = (float*)alloc((size_t)TC * BB * HH * 4);
  u16* S1 = (u16*)alloc((size_t)TC * BB * HH * 2);
  u16* S2 = (u16*)alloc((size_t)TC * BB * HH * 2);
  u16* S3 = (u16*)alloc((size_t)TC * BB * HH * 2);
  float* Rbuf = (float*)alloc((size_t)TC * BB * 128 * 4);

  // weight prep (runs every call; ~3MB of work)
  wsplit_kernel<<<dim3((512 * 128) / 256), dim3(256), 0, stream>>>(W1, W1Th, W1Tl, 120, 512, 7);
  wsplit_kernel<<<dim3((512 * 512) / 256), dim3(256), 0, stream>>>(W2, W2Th, W2Tl, 512, 512, 9);
  wsplit_kernel<<<dim3((512 * 512) / 256), dim3(256), 0, stream>>>(W3, W3Th, W3Tl, 512, 512, 9);
  wsplit_kernel<<<dim3((128 * 512) / 256), dim3(256), 0, stream>>>(Wr, WrTh, WrTl, 512, 12, 9);

  const int NC = TT / TC;
  for (int c = 0; c < NC; ++c) {
    int t0 = c * TC;
    int Mc = TC * BB;
    int first = (c == 0) ? 1 : 0;
    xsplit_kernel<<<dim3(TC * 512), dim3(256), 0, stream>>>(x, xh, xl, t0);
    gemm_tile<3><<<dim3((Mc / 128) * 4), dim3(256), 0, stream>>>(
        xh, xl, W1Th, W1Tl, Ibuf, Mc, 512, 128, 4);
    lif_kernel<<<dim3(512), dim3(256), 0, stream>>>(
        (const float4*)Ibuf, b1, v1, (ushort4*)S1, TC, first);
    gemm_tile<2><<<dim3((Mc / 128) * 4), dim3(256), 0, stream>>>(
        S1, nullptr, W2Th, W2Tl, Ibuf, Mc, 512, 512, 4);
    lif_kernel<<<dim3(512), dim3(256), 0, stream>>>(
        (const float4*)Ibuf, b2, v2, (ushort4*)S2, TC, first);
    gemm_tile<2><<<dim3((Mc / 128) * 4), dim3(256), 0, stream>>>(
        S2, nullptr, W3Th, W3Tl, Ibuf, Mc, 512, 512, 4);
    lif_kernel<<<dim3(512), dim3(256), 0, stream>>>(
        (const float4*)Ibuf, b3, v3, (ushort4*)S3, TC, first);
    gemm_tile<2><<<dim3(Mc / 128), dim3(256), 0, stream>>>(
        S3, nullptr, WrTh, WrTl, Rbuf, Mc, 128, 512, 1);
    memscan_kernel<<<dim3(4), dim3(256), 0, stream>>>(
        Rbuf, br, tau, mstate, sstate, TC, first);
  }
  finalize_kernel<<<dim3(4), dim3(256), 0, stream>>>(sstate, out);
}

// Round 2
// 504.431 us; speedup vs baseline: 1.3665x; 1.3665x over previous
//
#include <hip/hip_runtime.h>
#include <cstdint>
#include <cstddef>

using u16 = unsigned short;
typedef float f32x4 __attribute__((ext_vector_type(4)));
typedef __bf16 bf16x8 __attribute__((ext_vector_type(8)));

constexpr int BB = 1024;   // batch
constexpr int TT = 100;    // timesteps
constexpr int MMIN = 120;  // input features
constexpr int HH = 512;    // hidden
constexpr int DD = 12;     // output classes
constexpr int SEGL = 5;    // memscan segment length
constexpr int NSEG = TT / SEGL;

__device__ __forceinline__ u16 f2bf_rne(float x) {
  unsigned u = __float_as_uint(x);
  unsigned r = (u + 0x7FFFu + ((u >> 16) & 1u)) >> 16;
  return (u16)r;
}
__device__ __forceinline__ float bf2f(u16 u) {
  return __uint_as_float(((unsigned)u) << 16);
}

// ---------- weight transpose + hi/lo split:  T[n][k] = W[k][n] ----------
__global__ __launch_bounds__(256) void wsplit_kernel(
    const float* __restrict__ W, u16* __restrict__ Thi, u16* __restrict__ Tlo,
    int K, int N, int kp_shift) {
  int gid = blockIdx.x * 256 + threadIdx.x;
  int KP = 1 << kp_shift;
  int k = gid & (KP - 1);
  int n = gid >> kp_shift;
  float v = 0.0f;
  if (k < K && n < N) v = W[(size_t)k * N + n];
  u16 hi = f2bf_rne(v);
  Thi[gid] = hi;
  Tlo[gid] = f2bf_rne(v - bf2f(hi));
}

// ---------- x: (B,1,T,M) -> rows r=t*B+b of [r][128] (pad 120->128), hi/lo split ----------
__global__ __launch_bounds__(256) void xsplit_kernel(
    const float* __restrict__ x, u16* __restrict__ xhi, u16* __restrict__ xlo, int t0) {
  int gid = blockIdx.x * 256 + threadIdx.x;
  int m = gid & 127;
  int r = gid >> 7;               // local row within chunk
  int b = r & (BB - 1);
  int t = t0 + (r >> 10);
  float v = 0.0f;
  if (m < MMIN) v = x[(size_t)b * (TT * MMIN) + (size_t)t * MMIN + m];
  u16 hi = f2bf_rne(v);
  xhi[gid] = hi;
  xlo[gid] = f2bf_rne(v - bf2f(hi));
}

// ---------- async global->LDS ----------
typedef const __attribute__((address_space(1))) unsigned int gas_uint;
typedef __attribute__((address_space(3))) unsigned int las_uint;

__device__ __forceinline__ void gl_lds16(const void* g, void* l) {
  __builtin_amdgcn_global_load_lds((gas_uint*)g, (las_uint*)l, 16, 0, 0);
}

// ---------- 2-phase split-precision MFMA GEMM ----------
// A: MxK row-major bf16.  Bhi/Blo: NxK row-major bf16 (B^T).  C: MxN f32.
// BK=32, double-buffered LDS, counted vmcnt prefetch, XCD swizzle,
// LDS chunk swizzle c ^= (r>>1)&3 (conflict-free for 64B rows).
template <int TERMS>
__global__ __launch_bounds__(256) void gemm2p(
    const u16* __restrict__ Ahi, const u16* __restrict__ Alo,
    const u16* __restrict__ Bhi, const u16* __restrict__ Blo,
    float* __restrict__ C, int M, int N, int K, int Nt) {
  constexpr int NTILE = (TERMS == 3) ? 4 : 3;
  __shared__ __align__(16) u16 lds[2][NTILE][4096];   // 48KB or 64KB

  const int tid = threadIdx.x;
  // bijective XCD-chunk swizzle (gridDim.x % 8 == 0 by construction)
  const int nwg = gridDim.x;
  const int cpx = nwg >> 3;
  const int bid = (blockIdx.x & 7) * cpx + (blockIdx.x >> 3);
  const int bn = bid % Nt;
  const int bm = bid / Nt;
  const int lane = tid & 63;
  const int wv = tid >> 6;
  const int wm = wv >> 1, wn = wv & 1;
  const int lr = lane & 15, lg = lane >> 4;

  const size_t arow0 = (size_t)bm * 128;
  const size_t brow0 = (size_t)bn * 128;

  // per-thread precomputed staging addresses
  int off16[2];
  const u16 *gA[2], *gAl[2], *gBh[2], *gBl[2];
#pragma unroll
  for (int p = 0; p < 2; ++p) {
    int li = (p << 8) + tid;         // 16B-chunk index 0..511
    int r = li >> 2, c = li & 3;
    int cs = c ^ ((r >> 1) & 3);
    off16[p] = (li & ~63) * 8;       // u16 units; HW adds lane*16B
    gA[p]  = Ahi + (arow0 + (size_t)r) * (size_t)K + (size_t)cs * 8;
    gBh[p] = Bhi + (brow0 + (size_t)r) * (size_t)K + (size_t)cs * 8;
    gBl[p] = Blo + (brow0 + (size_t)r) * (size_t)K + (size_t)cs * 8;
    if constexpr (TERMS == 3)
      gAl[p] = Alo + (arow0 + (size_t)r) * (size_t)K + (size_t)cs * 8;
  }

  auto stage = [&](int s_) {
    const int k0 = s_ << 5;
    u16* base = &lds[s_ & 1][0][0];
#pragma unroll
    for (int p = 0; p < 2; ++p) gl_lds16(gA[p] + k0, base + off16[p]);
#pragma unroll
    for (int p = 0; p < 2; ++p) gl_lds16(gBh[p] + k0, base + 4096 + off16[p]);
#pragma unroll
    for (int p = 0; p < 2; ++p) gl_lds16(gBl[p] + k0, base + 8192 + off16[p]);
    if constexpr (TERMS == 3) {
#pragma unroll
      for (int p = 0; p < 2; ++p) gl_lds16(gAl[p] + k0, base + 12288 + off16[p]);
    }
  };

  f32x4 acc[4][4];
#pragma unroll
  for (int i = 0; i < 4; ++i)
#pragma unroll
    for (int j = 0; j < 4; ++j) acc[i][j] = (f32x4)0.0f;

  const int NS = K >> 5;
  stage(0);
  for (int s = 0; s < NS; ++s) {
    if (s + 1 < NS) {
      stage(s + 1);
      if constexpr (TERMS == 3) asm volatile("s_waitcnt vmcnt(8)" ::: "memory");
      else                      asm volatile("s_waitcnt vmcnt(6)" ::: "memory");
    } else {
      asm volatile("s_waitcnt vmcnt(0)" ::: "memory");
    }
    __builtin_amdgcn_sched_barrier(0);
    __builtin_amdgcn_s_barrier();           // buf[s&1] ready for all waves
    __builtin_amdgcn_sched_barrier(0);

    const u16* sAh = &lds[s & 1][0][0];
    const u16* sBh = &lds[s & 1][1][0];
    const u16* sBl = &lds[s & 1][2][0];

    bf16x8 a0[4], a1[4], bh[4], bl[4];
#pragma unroll
    for (int mf = 0; mf < 4; ++mf) {
      int r = wm * 64 + mf * 16 + lr;
      int o = r * 32 + (((lg ^ (r >> 1)) & 3) << 3);
      a0[mf] = *(const bf16x8*)&sAh[o];
      if constexpr (TERMS == 3) a1[mf] = *(const bf16x8*)&sAh[3 * 4096 + o];
    }
#pragma unroll
    for (int nf = 0; nf < 4; ++nf) {
      int r = wn * 64 + nf * 16 + lr;
      int o = r * 32 + (((lg ^ (r >> 1)) & 3) << 3);
      bh[nf] = *(const bf16x8*)&sBh[o];
      bl[nf] = *(const bf16x8*)&sBl[o];
    }
#pragma unroll
    for (int mf = 0; mf < 4; ++mf)
#pragma unroll
      for (int nf = 0; nf < 4; ++nf) {
        acc[mf][nf] = __builtin_amdgcn_mfma_f32_16x16x32_bf16(a0[mf], bh[nf], acc[mf][nf], 0, 0, 0);
        acc[mf][nf] = __builtin_amdgcn_mfma_f32_16x16x32_bf16(a0[mf], bl[nf], acc[mf][nf], 0, 0, 0);
        if constexpr (TERMS == 3)
          acc[mf][nf] = __builtin_amdgcn_mfma_f32_16x16x32_bf16(a1[mf], bh[nf], acc[mf][nf], 0, 0, 0);
      }

    __builtin_amdgcn_sched_barrier(0);
    asm volatile("s_waitcnt lgkmcnt(0)" ::: "memory");
    __builtin_amdgcn_sched_barrier(0);
    __builtin_amdgcn_s_barrier();           // all waves done reading buf[s&1]
    __builtin_amdgcn_sched_barrier(0);
  }

  // ---- epilogue: LDS-bounce transpose -> coalesced float4 stores ----
  float* ep = (float*)&lds[0][0][0];        // needs 64*132*4 = 33.8KB
#pragma unroll
  for (int h = 0; h < 2; ++h) {
    __syncthreads();
    if (wm == h) {
#pragma unroll
      for (int mf = 0; mf < 4; ++mf)
#pragma unroll
        for (int nf = 0; nf < 4; ++nf) {
          int col = wn * 64 + nf * 16 + lr;
#pragma unroll
          for (int j = 0; j < 4; ++j)
            ep[(mf * 16 + lg * 4 + j) * 132 + col] = acc[mf][nf][j];
        }
    }
    __syncthreads();
    int row = tid >> 5, grp = tid & 31;
#pragma unroll
    for (int it = 0; it < 8; ++it) {
      int rr = it * 8 + row;
      float4 v = *(const float4*)&ep[rr * 132 + grp * 4];
      *(float4*)&C[(arow0 + (size_t)h * 64 + rr) * (size_t)N + brow0 + grp * 4] = v;
    }
  }
}

// ---------- LIF elementwise scan over the chunk's timesteps ----------
__global__ __launch_bounds__(256) void lif_kernel(
    const float4* __restrict__ I, const float* __restrict__ bias,
    float* __restrict__ vstate, ushort4* __restrict__ S, int TC, int firstc) {
  int gid = blockIdx.x * 256 + threadIdx.x;   // B*H/4 = 131072 threads
  int h4 = gid & 127;
  int b = gid >> 7;
  float4 bi = ((const float4*)bias)[h4];
  float4 v;
  if (firstc) { v.x = 0.f; v.y = 0.f; v.z = 0.f; v.w = 0.f; }
  else v = ((const float4*)vstate)[gid];
  for (int t = 0; t < TC; ++t) {
    size_t o = ((size_t)t * BB + b) * 128 + h4;   // float4 units
    float4 iv = I[o];
    ushort4 s;
    v.x += (iv.x + bi.x - v.x) * 0.5f;
    v.y += (iv.y + bi.y - v.y) * 0.5f;
    v.z += (iv.z + bi.z - v.z) * 0.5f;
    v.w += (iv.w + bi.w - v.w) * 0.5f;
    s.x = (v.x >= 1.0f) ? (u16)0x3F80 : (u16)0;
    s.y = (v.y >= 1.0f) ? (u16)0x3F80 : (u16)0;
    s.z = (v.z >= 1.0f) ? (u16)0x3F80 : (u16)0;
    s.w = (v.w >= 1.0f) ? (u16)0x3F80 : (u16)0;
    if (v.x >= 1.0f) v.x = 0.0f;
    if (v.y >= 1.0f) v.y = 0.0f;
    if (v.z >= 1.0f) v.z = 0.0f;
    if (v.w >= 1.0f) v.w = 0.0f;
    S[o] = s;
  }
  ((float4*)vstate)[gid] = v;
}

// ---------- readout EMA: per-segment partials (mem-in = 0) ----------
__global__ __launch_bounds__(256) void memseg_kernel(
    const float* __restrict__ R, const float* __restrict__ br,
    const float* __restrict__ tau, float* __restrict__ qbuf,
    float* __restrict__ sbuf, int t0) {
  int gid = blockIdx.x * 256 + threadIdx.x;   // nseg_local * 1024 threads
  int b = gid & 1023;
  int sg = gid >> 10;                          // local segment index
  float al[DD], bb[DD], m[DD], s[DD];
#pragma unroll
  for (int d = 0; d < DD; ++d) {
    al[d] = 1.0f / (1.0f + expf(-tau[d]));
    bb[d] = br[d];
    m[d] = 0.0f; s[d] = 0.0f;
  }
  for (int i = 0; i < SEGL; ++i) {
    int t = sg * SEGL + i;                     // local t within chunk
    const float4* q = (const float4*)(R + ((size_t)t * BB + b) * 128);
    float4 q0 = q[0], q1 = q[1], q2 = q[2];
    float r[DD] = {q0.x, q0.y, q0.z, q0.w, q1.x, q1.y, q1.z, q1.w, q2.x, q2.y, q2.z, q2.w};
#pragma unroll
    for (int d = 0; d < DD; ++d) {
      float rv = r[d] + bb[d];
      m[d] = m[d] * al[d] + (1.0f - al[d]) * rv;
      s[d] += m[d];
    }
  }
  int gseg = t0 / SEGL + sg;
#pragma unroll
  for (int d = 0; d < DD; ++d) {
    qbuf[((size_t)gseg * BB + b) * DD + d] = m[d];
    sbuf[((size_t)gseg * BB + b) * DD + d] = s[d];
  }
}

// ---------- combine segments + mean + log_softmax ----------
__global__ __launch_bounds__(256) void memcombine_kernel(
    const float* __restrict__ qbuf, const float* __restrict__ sbuf,
    const float* __restrict__ tau, float* __restrict__ out) {
  int b = blockIdx.x * 256 + threadIdx.x;      // 1024 threads
  float al[DD], pL[DD], geo[DD], mem[DD], sum[DD];
#pragma unroll
  for (int d = 0; d < DD; ++d) {
    al[d] = 1.0f / (1.0f + expf(-tau[d]));
    float pl = 1.0f, g = 0.0f;
#pragma unroll
    for (int j = 0; j < SEGL; ++j) { pl *= al[d]; g += pl; }
    pL[d] = pl; geo[d] = g;
    mem[d] = 0.0f; sum[d] = 0.0f;
  }
  for (int g = 0; g < NSEG; ++g) {
    size_t o = ((size_t)g * BB + b) * DD;
#pragma unroll
    for (int d = 0; d < DD; ++d) {
      sum[d] += sbuf[o + d] + geo[d] * mem[d];
      mem[d] = pL[d] * mem[d] + qbuf[o + d];
    }
  }
  float l[DD];
#pragma unroll
  for (int d = 0; d < DD; ++d) l[d] = sum[d] * (1.0f / (float)TT);
  float mx = l[0];
#pragma unroll
  for (int d = 1; d < DD; ++d) mx = fmaxf(mx, l[d]);
  float se = 0.0f;
#pragma unroll
  for (int d = 0; d < DD; ++d) se += expf(l[d] - mx);
  float lse = logf(se);
#pragma unroll
  for (int d = 0; d < DD; ++d) out[b * DD + d] = l[d] - mx - lse;
}

extern "C" void kernel_launch(void* const* d_in, const int* in_sizes, int n_in,
                              void* d_out, int out_size, void* d_ws, size_t ws_size,
                              hipStream_t stream) {
  (void)in_sizes; (void)n_in; (void)out_size;
  const float* x   = (const float*)d_in[0];
  const float* W1  = (const float*)d_in[1];
  const float* b1  = (const float*)d_in[2];
  const float* W2  = (const float*)d_in[3];
  const float* b2  = (const float*)d_in[4];
  const float* W3  = (const float*)d_in[5];
  const float* b3  = (const float*)d_in[6];
  const float* Wr  = (const float*)d_in[7];
  const float* br  = (const float*)d_in[8];
  const float* tau = (const float*)d_in[9];
  float* out = (float*)d_out;

  // largest TC (divides 100, multiple of 5) whose aliased workspace fits:
  // per-t: union(xh,xl | S) = 1MB + Ibuf(>=R) = 2MB  ->  3MB/t
  const size_t fixed_bytes = (size_t)12 << 20;
  const size_t per_tc = (size_t)3 << 20;
  int TC = 5;
  const int cands[6] = {100, 50, 25, 20, 10, 5};
  for (int i = 0; i < 6; ++i) {
    if (fixed_bytes + (size_t)cands[i] * per_tc <= ws_size) { TC = cands[i]; break; }
  }

  char* base = (char*)d_ws;
  size_t off = 0;
  auto alloc = [&](size_t bytes) -> char* {
    char* p = base + off;
    off += (bytes + 255) & ~(size_t)255;
    return p;
  };

  u16* W1Th = (u16*)alloc(512 * 128 * 2);
  u16* W1Tl = (u16*)alloc(512 * 128 * 2);
  u16* W2Th = (u16*)alloc(512 * 512 * 2);
  u16* W2Tl = (u16*)alloc(512 * 512 * 2);
  u16* W3Th = (u16*)alloc(512 * 512 * 2);
  u16* W3Tl = (u16*)alloc(512 * 512 * 2);
  u16* WrTh = (u16*)alloc(128 * 512 * 2);
  u16* WrTl = (u16*)alloc(128 * 512 * 2);
  float* v1 = (float*)alloc((size_t)BB * HH * 4);
  float* v2 = (float*)alloc((size_t)BB * HH * 4);
  float* v3 = (float*)alloc((size_t)BB * HH * 4);
  float* qbuf = (float*)alloc((size_t)NSEG * BB * DD * 4);
  float* sbuf = (float*)alloc((size_t)NSEG * BB * DD * 4);
  // union region: xh | xl | S   (1MB per timestep)
  u16* U  = (u16*)alloc((size_t)TC * BB * HH * 2);
  u16* xh = U;
  u16* xl = U + (size_t)TC * BB * 128;
  u16* S  = U;
  // Ibuf (2MB/t); R aliases its head (0.5MB/t)
  float* Ibuf = (float*)alloc((size_t)TC * BB * HH * 4);
  float* Rbuf = Ibuf;

  wsplit_kernel<<<dim3((512 * 128) / 256), dim3(256), 0, stream>>>(W1, W1Th, W1Tl, 120, 512, 7);
  wsplit_kernel<<<dim3((512 * 512) / 256), dim3(256), 0, stream>>>(W2, W2Th, W2Tl, 512, 512, 9);
  wsplit_kernel<<<dim3((512 * 512) / 256), dim3(256), 0, stream>>>(W3, W3Th, W3Tl, 512, 512, 9);
  wsplit_kernel<<<dim3((128 * 512) / 256), dim3(256), 0, stream>>>(Wr, WrTh, WrTl, 512, 12, 9);

  const int NC = TT / TC;
  for (int c = 0; c < NC; ++c) {
    int t0 = c * TC;
    int Mc = TC * BB;
    int first = (c == 0) ? 1 : 0;
    xsplit_kernel<<<dim3(TC * 512), dim3(256), 0, stream>>>(x, xh, xl, t0);
    gemm2p<3><<<dim3((Mc / 128) * 4), dim3(256), 0, stream>>>(
        xh, xl, W1Th, W1Tl, Ibuf, Mc, 512, 128, 4);
    lif_kernel<<<dim3(512), dim3(256), 0, stream>>>(
        (const float4*)Ibuf, b1, v1, (ushort4*)S, TC, first);
    gemm2p<2><<<dim3((Mc / 128) * 4), dim3(256), 0, stream>>>(
        S, nullptr, W2Th, W2Tl, Ibuf, Mc, 512, 512, 4);
    lif_kernel<<<dim3(512), dim3(256), 0, stream>>>(
        (const float4*)Ibuf, b2, v2, (ushort4*)S, TC, first);
    gemm2p<2><<<dim3((Mc / 128) * 4), dim3(256), 0, stream>>>(
        S, nullptr, W3Th, W3Tl, Ibuf, Mc, 512, 512, 4);
    lif_kernel<<<dim3(512), dim3(256), 0, stream>>>(
        (const float4*)Ibuf, b3, v3, (ushort4*)S, TC, first);
    gemm2p<2><<<dim3(Mc / 128), dim3(256), 0, stream>>>(
        S, nullptr, WrTh, WrTl, Rbuf, Mc, 128, 512, 1);
    memseg_kernel<<<dim3((TC / SEGL) * 4), dim3(256), 0, stream>>>(
        Rbuf, br, tau, qbuf, sbuf, t0);
  }
  memcombine_kernel<<<dim3(4), dim3(256), 0, stream>>>(qbuf, sbuf, tau, out);
}